// Round 1
// baseline (2284.022 us; speedup 1.0000x reference)
//
#include <hip/hip_runtime.h>
#include <hip/hip_bf16.h>

// Problem: B=1024, C=512, H=7, W=7; weight (256,3,3,512); out (1024,512,7,7).
// O[b,i,h,p] = sum_{l,j,k} W[l,j,k,i] * S_{b,h}[l*3+j][p+k]
// S[c][t] (t in [0,9)): t=0,8 -> 0; t in [1,7]: V[b,l,h,j,(t-2) mod 7]
// V[b,l,h,j,w] = x[b,l,r1,w]*[0<=r1<7] + x[b,256+l,r2,w]*[0<=r2<7]
//   r1 = h+j-1, r2 = ((h-1) mod 7) + j - 1

__global__ __launch_bounds__(256) void fused_shift_conv_f32(
    const float* __restrict__ x,    // (1024,512,7,7)
    const float* __restrict__ Wg,   // (256,3,3,512) -> flat [(l*9+j*3+k)*512 + i]
    float* __restrict__ out)        // (1024,512,7,7)
{
    __shared__ float S[768 * 10];   // row stride 10 floats

    const int tid = threadIdx.x;
    const int bh  = blockIdx.x;
    const int b   = bh / 7;
    const int h   = bh - 7 * b;
    const int hm  = (h + 6) % 7;

    // ---- stage S ----
    for (int q = tid; q < 768; q += 256) {
        const int l = q / 3;
        const int j = q - 3 * l;
        const int r1 = h + j - 1;
        const int r2 = hm + j - 1;
        float row[7] = {0.f, 0.f, 0.f, 0.f, 0.f, 0.f, 0.f};
        if (r1 >= 0 && r1 < 7) {
            const float* p1 = x + (((size_t)b * 512 + l) * 7 + r1) * 7;
            #pragma unroll
            for (int w = 0; w < 7; ++w) row[w] += p1[w];
        }
        if (r2 >= 0 && r2 < 7) {
            const float* p2 = x + (((size_t)b * 512 + 256 + l) * 7 + r2) * 7;
            #pragma unroll
            for (int w = 0; w < 7; ++w) row[w] += p2[w];
        }
        float* Sc = &S[q * 10];
        Sc[0] = 0.f;
        Sc[8] = 0.f;
        // t = (w+1)%7 + 1 places V[..,w] at its rolled window slot
        #pragma unroll
        for (int w = 0; w < 7; ++w) Sc[(w + 1) % 7 + 1] = row[w];
    }
    __syncthreads();

    // ---- compute: this thread covers i = tid and i = tid + 256, all 7 p ----
    float acc0[7] = {0.f, 0.f, 0.f, 0.f, 0.f, 0.f, 0.f};
    float acc1[7] = {0.f, 0.f, 0.f, 0.f, 0.f, 0.f, 0.f};

    const float* wbase = Wg + tid;
    for (int c = 0; c < 768; ++c) {
        const float* Sc = &S[c * 10];
        float s[9];
        #pragma unroll
        for (int t = 0; t < 9; ++t) s[t] = Sc[t];

        const float* wr = wbase + (size_t)c * 3 * 512;
        const float w00 = wr[0],    w01 = wr[256];
        const float w10 = wr[512],  w11 = wr[768];
        const float w20 = wr[1024], w21 = wr[1280];

        #pragma unroll
        for (int p = 0; p < 7; ++p) {
            acc0[p] += s[p] * w00 + s[p + 1] * w10 + s[p + 2] * w20;
            acc1[p] += s[p] * w01 + s[p + 1] * w11 + s[p + 2] * w21;
        }
    }

    // ---- store: out[((b*512+i)*7+h)*7+p] ----
    float* op0 = out + (((size_t)b * 512 + tid) * 7 + h) * 7;
    #pragma unroll
    for (int p = 0; p < 7; ++p) op0[p] = acc0[p];
    float* op1 = op0 + (size_t)256 * 49;
    #pragma unroll
    for (int p = 0; p < 7; ++p) op1[p] = acc1[p];
}

extern "C" void kernel_launch(void* const* d_in, const int* in_sizes, int n_in,
                              void* d_out, int out_size, void* d_ws, size_t ws_size,
                              hipStream_t stream) {
    const float* x  = (const float*)d_in[0];  // 1024*512*7*7 fp32
    const float* Wg = (const float*)d_in[1];  // 256*3*3*512 fp32
    float* out = (float*)d_out;               // 1024*512*7*7 fp32

    dim3 grid(1024 * 7);
    dim3 block(256);
    fused_shift_conv_f32<<<grid, block, 0, stream>>>(x, Wg, out);
}

// Round 2
// 440.785 us; speedup vs baseline: 5.1817x; 5.1817x over previous
//
#include <hip/hip_runtime.h>
#include <hip/hip_bf16.h>

// O[b,i,h,p] = sum_{c=l*3+j in 768, tap in 3} W[l,j,tap,i] * S_{b,h}[c][p+tap]
// S[c][t]: t=0,8,9 -> 0; t=(w+1)%7+1 <- V[c][w]
// V[c][w] = x[b,l,r1,w]*[0<=r1<7] + x[b,256+l,r2,w]*[0<=r2<7],
//   r1 = h+j-1, r2 = ((h+6)%7)+j-1            (verified correct in round 1)
//
// GEMM view: M = 1024*7*8 (p padded to 8), N = 512, K = 2304 (kk = tap*768+c)
//   A[m,kk] = S_{bh(m)}[c][p(m)+tap]  (implicit, built per-chunk in LDS)
//   Bt[n,kk] = W2[i][kk] prepped once into d_ws as bf16.

typedef __bf16 bf16x8 __attribute__((ext_vector_type(8)));
typedef float f32x4 __attribute__((ext_vector_type(4)));

__global__ __launch_bounds__(256) void prep_w(const float* __restrict__ Wg,
                                              __bf16* __restrict__ W2) {
    int idx = blockIdx.x * 256 + threadIdx.x;     // over 512*2304
    int i = idx / 2304;
    int kk = idx - i * 2304;
    int tap = kk / 768;
    int c = kk - tap * 768;
    W2[idx] = (__bf16)Wg[(c * 3 + tap) * 512 + i];
}

__global__ __launch_bounds__(256) void gemm_shift(const float* __restrict__ x,
                                                  const __bf16* __restrict__ W2,
                                                  float* __restrict__ out) {
    __shared__ __bf16 T[16 * 10 * 40];   // [bh16][t10][c32], c-row stride 40 bf16
    __shared__ __bf16 Bt[128 * 104];     // [n128][tap*32+c], row stride 104 bf16

    const int tid = threadIdx.x;
    const int mb = blockIdx.x >> 2;      // 448 M-blocks (16 bh pairs each)
    const int nb = blockIdx.x & 3;       // 4 N-blocks of 128 i
    const int i0 = nb * 128;

    // ---- per-thread T-staging constants (2 (bh,c) pairs per thread) ----
    const int cl  = tid & 31;            // c within chunk
    const int bh0 = tid >> 5;            // bh_local and bh_local+8
    const int bhg0 = mb * 16 + bh0;
    const int bhg1 = bhg0 + 8;
    const int b0 = bhg0 / 7, h0 = bhg0 - 7 * b0;
    const int b1 = bhg1 / 7, h1 = bhg1 - 7 * b1;
    const int hm0 = (h0 + 6) % 7, hm1 = (h1 + 6) % 7;

    // zero all of T once (covers the always-zero t=0,8,9 rows; t=1..7 rewritten per chunk)
    for (int q = tid; q < 16 * 10 * 40 / 2; q += 256) ((int*)T)[q] = 0;

    // ---- wave/frag constants ----
    const int lane = tid & 63;
    const int wave = tid >> 6;
    const int wm = wave >> 1;            // 2x2 wave grid, each 64x64
    const int wn = wave & 1;
    const int ln15 = lane & 15;
    const int g = lane >> 4;

    f32x4 acc[4][4];
    #pragma unroll
    for (int a = 0; a < 4; ++a)
        #pragma unroll
        for (int b = 0; b < 4; ++b) acc[a][b] = (f32x4){0.f, 0.f, 0.f, 0.f};

    for (int chunk = 0; chunk < 24; ++chunk) {
        // ---- stage T: V rows for (bh0,cl) and (bh0+8,cl) ----
        const int cg = chunk * 32 + cl;
        const int l = cg / 3;
        const int j = cg - 3 * l;
        {
            const int r1 = h0 + j - 1, r2 = hm0 + j - 1;
            float v[7] = {0.f, 0.f, 0.f, 0.f, 0.f, 0.f, 0.f};
            if (r1 >= 0 && r1 < 7) {
                const float* p1 = x + (((size_t)b0 * 512 + l) * 7 + r1) * 7;
                #pragma unroll
                for (int w = 0; w < 7; ++w) v[w] += p1[w];
            }
            if (r2 >= 0 && r2 < 7) {
                const float* p2 = x + (((size_t)b0 * 512 + 256 + l) * 7 + r2) * 7;
                #pragma unroll
                for (int w = 0; w < 7; ++w) v[w] += p2[w];
            }
            #pragma unroll
            for (int w = 0; w < 7; ++w)
                T[bh0 * 400 + ((w + 1) % 7 + 1) * 40 + cl] = (__bf16)v[w];
        }
        {
            const int r1 = h1 + j - 1, r2 = hm1 + j - 1;
            float v[7] = {0.f, 0.f, 0.f, 0.f, 0.f, 0.f, 0.f};
            if (r1 >= 0 && r1 < 7) {
                const float* p1 = x + (((size_t)b1 * 512 + l) * 7 + r1) * 7;
                #pragma unroll
                for (int w = 0; w < 7; ++w) v[w] += p1[w];
            }
            if (r2 >= 0 && r2 < 7) {
                const float* p2 = x + (((size_t)b1 * 512 + 256 + l) * 7 + r2) * 7;
                #pragma unroll
                for (int w = 0; w < 7; ++w) v[w] += p2[w];
            }
            #pragma unroll
            for (int w = 0; w < 7; ++w)
                T[(bh0 + 8) * 400 + ((w + 1) % 7 + 1) * 40 + cl] = (__bf16)v[w];
        }

        // ---- stage Bt: 1536 x 16B units, 6 per thread ----
        #pragma unroll
        for (int it = 0; it < 6; ++it) {
            const int u = it * 256 + tid;        // u = tap*512 + n*4 + q
            const int tap = u >> 9;
            const int rem = u & 511;
            const int n = rem >> 2;
            const int q = rem & 3;
            const float4 val = *(const float4*)(W2 + (size_t)(i0 + n) * 2304 +
                                                tap * 768 + chunk * 32 + q * 8);
            *(float4*)(&Bt[n * 104 + tap * 32 + q * 8]) = val;
        }

        __syncthreads();

        // ---- MFMA: 3 taps x (4 Mfrag x 4 Nfrag) per wave ----
        #pragma unroll
        for (int tap = 0; tap < 3; ++tap) {
            bf16x8 af[4], bfr[4];
            #pragma unroll
            for (int mf = 0; mf < 4; ++mf) {
                const int bh_l = wm * 8 + mf * 2 + (ln15 >> 3);
                const int p = ln15 & 7;
                af[mf] = *(const bf16x8*)(&T[(bh_l * 10 + p + tap) * 40 + g * 8]);
            }
            #pragma unroll
            for (int nf = 0; nf < 4; ++nf) {
                const int n_l = wn * 64 + nf * 16 + ln15;
                bfr[nf] = *(const bf16x8*)(&Bt[n_l * 104 + tap * 32 + g * 8]);
            }
            #pragma unroll
            for (int mf = 0; mf < 4; ++mf)
                #pragma unroll
                for (int nf = 0; nf < 4; ++nf)
                    acc[mf][nf] = __builtin_amdgcn_mfma_f32_16x16x32_bf16(
                        af[mf], bfr[nf], acc[mf][nf], 0, 0, 0);
        }

        __syncthreads();
    }

    // ---- epilogue: D row = quad*4+reg, col = lane&15 ----
    #pragma unroll
    for (int mf = 0; mf < 4; ++mf) {
        #pragma unroll
        for (int r = 0; r < 4; ++r) {
            const int mrow = g * 4 + r;                  // 0..15
            const int Mg_l = wm * 64 + mf * 16 + mrow;
            const int p = Mg_l & 7;
            if (p == 7) continue;                        // padded row
            const int bh_l = Mg_l >> 3;
            const int bhg = mb * 16 + bh_l;
            const int b = bhg / 7;
            const int h = bhg - 7 * b;
            #pragma unroll
            for (int nf = 0; nf < 4; ++nf) {
                const int i = i0 + wn * 64 + nf * 16 + ln15;
                out[(((size_t)b * 512 + i) * 7 + h) * 7 + p] = acc[mf][nf][r];
            }
        }
    }
}

extern "C" void kernel_launch(void* const* d_in, const int* in_sizes, int n_in,
                              void* d_out, int out_size, void* d_ws, size_t ws_size,
                              hipStream_t stream) {
    const float* x  = (const float*)d_in[0];   // (1024,512,7,7) fp32
    const float* Wg = (const float*)d_in[1];   // (256,3,3,512) fp32
    float* out = (float*)d_out;                // (1024,512,7,7) fp32
    __bf16* W2 = (__bf16*)d_ws;                // 512*2304 bf16 = 2.36 MB

    prep_w<<<dim3(512 * 2304 / 256), dim3(256), 0, stream>>>(Wg, W2);
    gemm_shift<<<dim3(448 * 4), dim3(256), 0, stream>>>(x, W2, out);
}

// Round 3
// 381.931 us; speedup vs baseline: 5.9802x; 1.1541x over previous
//
#include <hip/hip_runtime.h>
#include <hip/hip_bf16.h>

// O[b,i,h,p] = sum_{c=l*3+j in 768, tap in 3} W[l,j,tap,i] * S_{b,h}[c][p+tap]
// S[c][t]: t=0,8,9 -> 0; t=(w+1)%7+1 <- V[c][w]
// V[c][w] = x[b,l,r1,w]*[0<=r1<7] + x[b,256+l,r2,w]*[0<=r2<7],
//   r1 = h+j-1, r2 = ((h+6)%7)+j-1            (verified rounds 1-2)
//
// Round 3: V is precomputed into d_ws as Vt[bh][r=t-1][c] bf16 (77 MB), so the
// GEMM's T-staging is 2 float4 loads + 2 ds_write_b128 per thread per chunk
// instead of 28 scalar global loads + 14 ds_write_b16.

typedef __bf16 bf16x8 __attribute__((ext_vector_type(8)));
typedef float f32x4 __attribute__((ext_vector_type(4)));

#define VT_OFFSET (4u << 20)                       // W2 at d_ws+0, Vt at d_ws+4MB
#define VT_BYTES  (7168ull * 7 * 768 * 2)          // 77,070,336
#define WS_NEED   (VT_OFFSET + VT_BYTES)

__global__ __launch_bounds__(256) void prep_w(const float* __restrict__ Wg,
                                              __bf16* __restrict__ W2) {
    int idx = blockIdx.x * 256 + threadIdx.x;      // over 512*2304
    int i = idx / 2304;
    int kk = idx - i * 2304;
    int tap = kk / 768;
    int c = kk - tap * 768;
    W2[idx] = (__bf16)Wg[(c * 3 + tap) * 512 + i];
}

// block per b (1024), thread = l (256). Reads x[b,l,:,:] and x[b,l+256,:,:]
// once; emits Vt[(b*7+h)*7 + r][c=l*3+j] for all h,j,w (r=(w+1)%7).
__global__ __launch_bounds__(256) void prep_v(const float* __restrict__ x,
                                              __bf16* __restrict__ Vt) {
    const int b = blockIdx.x;
    const int l = threadIdx.x;
    float xa[49], xb[49];
    const float* pa = x + ((size_t)b * 512 + l) * 49;
    const float* pb = x + ((size_t)b * 512 + 256 + l) * 49;
    #pragma unroll
    for (int q = 0; q < 49; ++q) xa[q] = pa[q];
    #pragma unroll
    for (int q = 0; q < 49; ++q) xb[q] = pb[q];

    #pragma unroll
    for (int h = 0; h < 7; ++h) {
        const int hm = (h + 6) % 7;
        #pragma unroll
        for (int j = 0; j < 3; ++j) {
            const int r1 = h + j - 1;              // compile-time per (h,j)
            const int r2 = hm + j - 1;
            __bf16* dst = Vt + (size_t)(b * 7 + h) * 7 * 768 + (l * 3 + j);
            #pragma unroll
            for (int w = 0; w < 7; ++w) {
                float v = 0.f;
                if (r1 >= 0 && r1 < 7) v += xa[r1 * 7 + w];
                if (r2 >= 0 && r2 < 7) v += xb[r2 * 7 + w];
                dst[(size_t)((w + 1) % 7) * 768] = (__bf16)v;
            }
        }
    }
}

__global__ __launch_bounds__(256) void gemm_vt(const __bf16* __restrict__ Vt,
                                               const __bf16* __restrict__ W2,
                                               float* __restrict__ out) {
    __shared__ __bf16 T[16 * 400];       // [bh16][t10][c32], t-stride 40 bf16
    __shared__ __bf16 Bt[128 * 104];     // [n128][tap*32+c], row stride 104 bf16

    const int tid = threadIdx.x;
    // XCD swizzle: the 4 N-siblings of one mb are g, g+8, g+16, g+24 -> same XCD
    const int g0 = blockIdx.x;
    const int nb = (g0 >> 3) & 3;
    const int mb = ((g0 >> 5) << 3) | (g0 & 7);
    const int i0 = nb * 128;

    // zero T once (rows t=0,8,9 stay zero; rows 1..7 are re-staged per chunk)
    for (int q = tid; q < 3200; q += 256) ((int*)T)[q] = 0;

    const int lane = tid & 63;
    const int wave = tid >> 6;
    const int wm = wave >> 1;            // 2x2 wave grid, each 64x64
    const int wn = wave & 1;
    const int ln15 = lane & 15;
    const int gq = lane >> 4;

    f32x4 acc[4][4];
    #pragma unroll
    for (int a = 0; a < 4; ++a)
        #pragma unroll
        for (int bq = 0; bq < 4; ++bq) acc[a][bq] = (f32x4){0.f, 0.f, 0.f, 0.f};

    __syncthreads();                     // T zeroing complete before staging

    for (int chunk = 0; chunk < 24; ++chunk) {
        // ---- stage T: 448 16B units (16 bh x 7 t x 4 q), 2 iters ----
        #pragma unroll
        for (int it = 0; it < 2; ++it) {
            const int u = it * 256 + tid;
            if (u < 448) {
                const int q = u & 3;
                const int tmp = u >> 2;          // 0..111
                const int t = tmp % 7;
                const int bh = tmp / 7;
                const float4 val = *(const float4*)(
                    Vt + (size_t)((mb * 16 + bh) * 7 + t) * 768 + chunk * 32 + q * 8);
                *(float4*)(&T[bh * 400 + (t + 1) * 40 + q * 8]) = val;
            }
        }
        // ---- stage Bt: 1536 16B units, 6 per thread ----
        #pragma unroll
        for (int it = 0; it < 6; ++it) {
            const int u = it * 256 + tid;        // u = tap*512 + n*4 + q
            const int tap = u >> 9;
            const int rem = u & 511;
            const int n = rem >> 2;
            const int q = rem & 3;
            const float4 val = *(const float4*)(W2 + (size_t)(i0 + n) * 2304 +
                                                tap * 768 + chunk * 32 + q * 8);
            *(float4*)(&Bt[n * 104 + tap * 32 + q * 8]) = val;
        }

        __syncthreads();

        // ---- MFMA: 3 taps x (4 Mfrag x 4 Nfrag) per wave ----
        #pragma unroll
        for (int tap = 0; tap < 3; ++tap) {
            bf16x8 af[4], bfr[4];
            #pragma unroll
            for (int mf = 0; mf < 4; ++mf) {
                const int bh_l = wm * 8 + mf * 2 + (ln15 >> 3);
                const int p = ln15 & 7;
                af[mf] = *(const bf16x8*)(&T[(bh_l * 10 + p + tap) * 40 + gq * 8]);
            }
            #pragma unroll
            for (int nf = 0; nf < 4; ++nf) {
                const int n_l = wn * 64 + nf * 16 + ln15;
                bfr[nf] = *(const bf16x8*)(&Bt[n_l * 104 + tap * 32 + gq * 8]);
            }
            #pragma unroll
            for (int mf = 0; mf < 4; ++mf)
                #pragma unroll
                for (int nf = 0; nf < 4; ++nf)
                    acc[mf][nf] = __builtin_amdgcn_mfma_f32_16x16x32_bf16(
                        af[mf], bfr[nf], acc[mf][nf], 0, 0, 0);
        }

        __syncthreads();
    }

    // ---- epilogue: D row = quad*4+reg, col = lane&15 ----
    #pragma unroll
    for (int mf = 0; mf < 4; ++mf) {
        #pragma unroll
        for (int r = 0; r < 4; ++r) {
            const int mrow = gq * 4 + r;                 // 0..15
            const int Mg_l = wm * 64 + mf * 16 + mrow;
            const int p = Mg_l & 7;
            if (p == 7) continue;                        // padded row
            const int bh_l = Mg_l >> 3;
            const int bhg = mb * 16 + bh_l;
            const int b = bhg / 7;
            const int h = bhg - 7 * b;
            #pragma unroll
            for (int nf = 0; nf < 4; ++nf) {
                const int i = i0 + wn * 64 + nf * 16 + ln15;
                out[(((size_t)b * 512 + i) * 7 + h) * 7 + p] = acc[mf][nf][r];
            }
        }
    }
}

// ---------------- fallback (round-2 implicit staging) if ws is small --------
__global__ __launch_bounds__(256) void gemm_shift(const float* __restrict__ x,
                                                  const __bf16* __restrict__ W2,
                                                  float* __restrict__ out) {
    __shared__ __bf16 T[16 * 10 * 40];
    __shared__ __bf16 Bt[128 * 104];

    const int tid = threadIdx.x;
    const int mb = blockIdx.x >> 2;
    const int nb = blockIdx.x & 3;
    const int i0 = nb * 128;

    const int cl  = tid & 31;
    const int bh0 = tid >> 5;
    const int bhg0 = mb * 16 + bh0;
    const int bhg1 = bhg0 + 8;
    const int b0 = bhg0 / 7, h0 = bhg0 - 7 * b0;
    const int b1 = bhg1 / 7, h1 = bhg1 - 7 * b1;
    const int hm0 = (h0 + 6) % 7, hm1 = (h1 + 6) % 7;

    for (int q = tid; q < 16 * 10 * 40 / 2; q += 256) ((int*)T)[q] = 0;

    const int lane = tid & 63;
    const int wave = tid >> 6;
    const int wm = wave >> 1;
    const int wn = wave & 1;
    const int ln15 = lane & 15;
    const int gq = lane >> 4;

    f32x4 acc[4][4];
    #pragma unroll
    for (int a = 0; a < 4; ++a)
        #pragma unroll
        for (int bq = 0; bq < 4; ++bq) acc[a][bq] = (f32x4){0.f, 0.f, 0.f, 0.f};

    __syncthreads();

    for (int chunk = 0; chunk < 24; ++chunk) {
        const int cg = chunk * 32 + cl;
        const int l = cg / 3;
        const int j = cg - 3 * l;
        {
            const int r1 = h0 + j - 1, r2 = hm0 + j - 1;
            float v[7] = {0.f, 0.f, 0.f, 0.f, 0.f, 0.f, 0.f};
            if (r1 >= 0 && r1 < 7) {
                const float* p1 = x + (((size_t)b0 * 512 + l) * 7 + r1) * 7;
                #pragma unroll
                for (int w = 0; w < 7; ++w) v[w] += p1[w];
            }
            if (r2 >= 0 && r2 < 7) {
                const float* p2 = x + (((size_t)b0 * 512 + 256 + l) * 7 + r2) * 7;
                #pragma unroll
                for (int w = 0; w < 7; ++w) v[w] += p2[w];
            }
            #pragma unroll
            for (int w = 0; w < 7; ++w)
                T[bh0 * 400 + ((w + 1) % 7 + 1) * 40 + cl] = (__bf16)v[w];
        }
        {
            const int r1 = h1 + j - 1, r2 = hm1 + j - 1;
            float v[7] = {0.f, 0.f, 0.f, 0.f, 0.f, 0.f, 0.f};
            if (r1 >= 0 && r1 < 7) {
                const float* p1 = x + (((size_t)b1 * 512 + l) * 7 + r1) * 7;
                #pragma unroll
                for (int w = 0; w < 7; ++w) v[w] += p1[w];
            }
            if (r2 >= 0 && r2 < 7) {
                const float* p2 = x + (((size_t)b1 * 512 + 256 + l) * 7 + r2) * 7;
                #pragma unroll
                for (int w = 0; w < 7; ++w) v[w] += p2[w];
            }
            #pragma unroll
            for (int w = 0; w < 7; ++w)
                T[(bh0 + 8) * 400 + ((w + 1) % 7 + 1) * 40 + cl] = (__bf16)v[w];
        }

        #pragma unroll
        for (int it = 0; it < 6; ++it) {
            const int u = it * 256 + tid;
            const int tap = u >> 9;
            const int rem = u & 511;
            const int n = rem >> 2;
            const int q = rem & 3;
            const float4 val = *(const float4*)(W2 + (size_t)(i0 + n) * 2304 +
                                                tap * 768 + chunk * 32 + q * 8);
            *(float4*)(&Bt[n * 104 + tap * 32 + q * 8]) = val;
        }

        __syncthreads();

        #pragma unroll
        for (int tap = 0; tap < 3; ++tap) {
            bf16x8 af[4], bfr[4];
            #pragma unroll
            for (int mf = 0; mf < 4; ++mf) {
                const int bh_l = wm * 8 + mf * 2 + (ln15 >> 3);
                const int p = ln15 & 7;
                af[mf] = *(const bf16x8*)(&T[(bh_l * 10 + p + tap) * 40 + gq * 8]);
            }
            #pragma unroll
            for (int nf = 0; nf < 4; ++nf) {
                const int n_l = wn * 64 + nf * 16 + ln15;
                bfr[nf] = *(const bf16x8*)(&Bt[n_l * 104 + tap * 32 + gq * 8]);
            }
            #pragma unroll
            for (int mf = 0; mf < 4; ++mf)
                #pragma unroll
                for (int nf = 0; nf < 4; ++nf)
                    acc[mf][nf] = __builtin_amdgcn_mfma_f32_16x16x32_bf16(
                        af[mf], bfr[nf], acc[mf][nf], 0, 0, 0);
        }

        __syncthreads();
    }

    #pragma unroll
    for (int mf = 0; mf < 4; ++mf) {
        #pragma unroll
        for (int r = 0; r < 4; ++r) {
            const int mrow = gq * 4 + r;
            const int Mg_l = wm * 64 + mf * 16 + mrow;
            const int p = Mg_l & 7;
            if (p == 7) continue;
            const int bh_l = Mg_l >> 3;
            const int bhg = mb * 16 + bh_l;
            const int b = bhg / 7;
            const int h = bhg - 7 * b;
            #pragma unroll
            for (int nf = 0; nf < 4; ++nf) {
                const int i = i0 + wn * 64 + nf * 16 + ln15;
                out[(((size_t)b * 512 + i) * 7 + h) * 7 + p] = acc[mf][nf][r];
            }
        }
    }
}

extern "C" void kernel_launch(void* const* d_in, const int* in_sizes, int n_in,
                              void* d_out, int out_size, void* d_ws, size_t ws_size,
                              hipStream_t stream) {
    const float* x  = (const float*)d_in[0];   // (1024,512,7,7) fp32
    const float* Wg = (const float*)d_in[1];   // (256,3,3,512) fp32
    float* out = (float*)d_out;                // (1024,512,7,7) fp32
    __bf16* W2 = (__bf16*)d_ws;                // 512*2304 bf16 = 2.36 MB

    prep_w<<<dim3(512 * 2304 / 256), dim3(256), 0, stream>>>(Wg, W2);

    if (ws_size >= WS_NEED) {
        __bf16* Vt = (__bf16*)((char*)d_ws + VT_OFFSET);
        prep_v<<<dim3(1024), dim3(256), 0, stream>>>(x, Vt);
        gemm_vt<<<dim3(448 * 4), dim3(256), 0, stream>>>(Vt, W2, out);
    } else {
        gemm_shift<<<dim3(448 * 4), dim3(256), 0, stream>>>(x, W2, out);
    }
}